// Round 10
// baseline (135.293 us; speedup 1.0000x reference)
//
#include <hip/hip_runtime.h>
#include <stdint.h>

// Problem constants: B=4, I=32, N=4096, D=64, TEM=1.0, WP=0.5
#define Bsz 4
#define Isz 32
#define Nsz 4096
#define Dsz 64
#define WPc 0.5f
#define ALPHA 1.2011224087864498f  // sqrt(log2(e)): folds 1/ln2 into the data
#define LN2 0.69314718055994531f
#define LSZ2 256                   // member-list capacity (mean 128, sd 11)
#define GBLK (Isz * Bsz * 2)       // gram grid: 2 row-chunks per (b,i)
#define NREP 3                     // DIAGNOSTIC: rowsum work replicated 3x

typedef __attribute__((ext_vector_type(8))) short short8;   // 8 bf16
typedef __attribute__((ext_vector_type(4))) float floatx4;  // MFMA C/D

__device__ inline uint16_t f2bf(float f) {
  uint32_t u = __float_as_uint(f);
  u += 0x7fffu + ((u >> 16) & 1u);  // RNE
  return (uint16_t)(u >> 16);
}
// exp2 via raw v_exp_f32; same op in rowsum and gram so negtot-negSub cancels.
__device__ inline float exp2_raw(float f) { return __builtin_amdgcn_exp2f(f); }

// async global->LDS DMA, 16B per lane: deposits at (wave-uniform base) + lane*16.
__device__ inline void load_lds16(const uint16_t* g, void* l) {
  __builtin_amdgcn_global_load_lds(
      (const __attribute__((address_space(1))) uint32_t*)g,
      (__attribute__((address_space(3))) uint32_t*)l, 16, 0, 0);
}

// ---------------------------------------------------------------------------
// Kernel 1: convert x -> bf16(ALPHA*x); zero negtot / accum / ticket; write
// the diagnostic rep-scales {1,0,0} (opaque to rowsum's compiler view).
// ---------------------------------------------------------------------------
__global__ __launch_bounds__(256) void prep_kernel(
    const float* __restrict__ x, uint16_t* __restrict__ xb,
    float* __restrict__ negtot, float* __restrict__ accum,
    int* __restrict__ ticket, float* __restrict__ scales) {
  const int t = threadIdx.x;
  const int blk = blockIdx.x;
  const int idx4 = (blk * 256 + t) * 4;
  const float4 v = *(const float4*)(x + idx4);
  ushort4 o;
  o.x = f2bf(v.x * ALPHA);
  o.y = f2bf(v.y * ALPHA);
  o.z = f2bf(v.z * ALPHA);
  o.w = f2bf(v.w * ALPHA);
  *(ushort4*)(xb + idx4) = o;
  if (blk < 64) {
    const int p = blk * 256 + t;  // 0..16383 rows
    negtot[p] = 0.f;
    if (p == 0) {
      accum[0] = 0.f;
      ticket[0] = 0;
      scales[0] = 1.f;
      scales[1] = 0.f;
      scales[2] = 0.f;
    }
  }
}

// ---------------------------------------------------------------------------
// Kernel 2 (DIAGNOSTIC build of round-9 rowsum4): identical structure, but
// the entire col-group pass runs NREP times. Rep r's row-sum is atomically
// added scaled by scales[r] = {1,0,0} (runtime values -> no dead-code elim;
// g*1 then +g*0 twice leaves negtot bit-identical to round 9).
// Purpose: total_dur = base + (NREP-1)*rowsum_time -> solve for rowsum_time.
// ---------------------------------------------------------------------------
__global__ __launch_bounds__(256) void rowsum4_kernel(
    const uint16_t* __restrict__ xb, float* __restrict__ negtot,
    const float* __restrict__ scales) {
  __shared__ uint4 sbuf[2][1024];  // 2 x 16 KB

  const int t = threadIdx.x;
  const int lane = t & 63;
  const int w = t >> 6;
  const int quad = lane >> 4;
  const int l15 = lane & 15;

  const int b = blockIdx.y;
  const int row0 = (blockIdx.x >> 3) * 128;  // 32 row-tiles
  const int cg0 = (blockIdx.x & 7) * 512;    // 8 col-groups x 512 cols
  const size_t bN = (size_t)b * Nsz;
  const uint16_t* xbB = xb + bN * Dsz;
  const int wrow0 = row0 + w * 32;

  // A fragments: this wave's 32 rows, kept in regs all kernel.
  short8 af[2][2];
#pragma unroll
  for (int rt = 0; rt < 2; ++rt)
#pragma unroll
    for (int kh = 0; kh < 2; ++kh)
      af[rt][kh] = *(const short8*)(xbB + (size_t)(wrow0 + rt * 16 + l15) * Dsz +
                                    quad * 8 + kh * 32);

  float sc[NREP];
#pragma unroll
  for (int r = 0; r < NREP; ++r) sc[r] = scales[r];

#pragma unroll 1
  for (int rep = 0; rep < NREP; ++rep) {
    float negAll[2][4] = {{0.f, 0.f, 0.f, 0.f}, {0.f, 0.f, 0.f, 0.f}};

    // stage chunk 0 (each wave DMAs its quarter: 4 x 1KB instructions)
#pragma unroll
    for (int k = 0; k < 4; ++k) {
      const int S = w * 256 + k * 64 + lane;
      const int col = S >> 3;
      const int u = (S & 7) ^ (col & 7);
      load_lds16(xbB + (size_t)(cg0 + col) * Dsz + u * 8,
                 (void*)((uint4*)sbuf[0] + w * 256 + k * 64));
    }
    __syncthreads();

#pragma unroll
    for (int it = 0; it < 4; ++it) {
      const int cur = it & 1;
      if (it < 3) {  // DMA next chunk into the other buffer
        const int c0 = cg0 + (it + 1) * 128;
#pragma unroll
        for (int k = 0; k < 4; ++k) {
          const int S = w * 256 + k * 64 + lane;
          const int col = S >> 3;
          const int u = (S & 7) ^ (col & 7);
          load_lds16(xbB + (size_t)(c0 + col) * Dsz + u * 8,
                     (void*)((uint4*)sbuf[cur ^ 1] + w * 256 + k * 64));
        }
      }
      // compute on sbuf[cur]: 8 col-tiles in 2 halves (limits acc VGPRs)
#pragma unroll
      for (int h = 0; h < 2; ++h) {
        short8 bf[4][2];
#pragma unroll
        for (int ci = 0; ci < 4; ++ci) {
          const int col = (h * 4 + ci) * 16 + l15;
#pragma unroll
          for (int kh = 0; kh < 2; ++kh) {
            const int u = quad + kh * 4;
            bf[ci][kh] = *(const short8*)&sbuf[cur][(col << 3) | (u ^ (col & 7))];
          }
        }
        floatx4 acc[2][4];
#pragma unroll
        for (int rt = 0; rt < 2; ++rt)
#pragma unroll
          for (int ci = 0; ci < 4; ++ci)
            acc[rt][ci] = (floatx4){0.f, 0.f, 0.f, 0.f};
#pragma unroll
        for (int kh = 0; kh < 2; ++kh)
#pragma unroll
          for (int ci = 0; ci < 4; ++ci)
#pragma unroll
            for (int rt = 0; rt < 2; ++rt)
              acc[rt][ci] = __builtin_amdgcn_mfma_f32_16x16x32_bf16(
                  af[rt][kh], bf[ci][kh], acc[rt][ci], 0, 0, 0);
#pragma unroll
        for (int ci = 0; ci < 4; ++ci)
#pragma unroll
          for (int rt = 0; rt < 2; ++rt)
#pragma unroll
            for (int r = 0; r < 4; ++r)
              negAll[rt][r] += exp2_raw(acc[rt][ci][r]);
      }
      __syncthreads();  // retire this chunk's reads + drain DMA into buf^1
    }

    // reduce over the 16 l15 lanes; one (scaled) atomic per row per rep.
#pragma unroll
    for (int rt = 0; rt < 2; ++rt)
#pragma unroll
      for (int r = 0; r < 4; ++r) {
        float g = negAll[rt][r];
#pragma unroll
        for (int m = 1; m < 16; m <<= 1) g += __shfl_xor(g, m, 64);
        if (l15 == 0)
          atomicAdd(&negtot[bN + wrow0 + rt * 16 + quad * 4 + r], g * sc[rep]);
      }
    __syncthreads();  // keep reps cleanly separated
  }
}

// ---------------------------------------------------------------------------
// Kernel 3: per-instance Gram + finalize (round-9 gram2, unchanged).
// ---------------------------------------------------------------------------
__global__ __launch_bounds__(256) void gram2_kernel(
    const uint16_t* __restrict__ xb, const uint8_t* __restrict__ label,
    const float* __restrict__ negtot, float* __restrict__ accum,
    int* __restrict__ ticket, float* __restrict__ out) {
  __shared__ int list[LSZ2];
  __shared__ int scnt;
  __shared__ uint4 grow[LSZ2 * 8];  // 32 KB swizzled member-row data
  __shared__ float sPos[4];
  __shared__ float sLn[4];

  const int t = threadIdx.x;
  const int lane = t & 63;
  const int w = t >> 6;
  const int quad = lane >> 4;
  const int l15 = lane & 15;
  const int i = blockIdx.x;
  const int b = blockIdx.y;
  const int rc = blockIdx.z;  // row-chunk 0/1
  const size_t bN = (size_t)b * Nsz;
  const uint16_t* xbB = xb + bN * Dsz;

  if (t == 0) scnt = 0;
  __syncthreads();
  {  // membership: 16 label bytes per thread
    const uint4 lv = ((const uint4*)(label + ((size_t)b * Isz + i) * Nsz))[t];
    const uint32_t words[4] = {lv.x, lv.y, lv.z, lv.w};
#pragma unroll
    for (int jw = 0; jw < 4; ++jw)
#pragma unroll
      for (int jb = 0; jb < 4; ++jb) {
        if ((words[jw] >> (jb * 8)) & 0xff) {
          const int idx = atomicAdd(&scnt, 1);
          if (idx < LSZ2) list[idx] = t * 16 + jw * 4 + jb;
        }
      }
  }
  __syncthreads();
  const int cnt = scnt;
  const int cntE = cnt < LSZ2 ? cnt : LSZ2;

  // stage member rows into swizzled LDS (once; shared by A and B frags)
  for (int s = t; s < cntE * 8; s += 256) {
    const int j = s >> 3, u = s & 7;
    grow[(j << 3) | (u ^ (j & 7))] =
        *(const uint4*)(xbB + (size_t)list[j] * Dsz + u * 8);
  }
  __syncthreads();

  const bool active = (cnt >= 5) && (rc * 128 < cntE);
  if (active) {
    // A fragments for this block's 128 rows (wave w: rows rc*128+w*32..+31)
    short8 af[2][2];
#pragma unroll
    for (int rt = 0; rt < 2; ++rt) {
      int ridx = rc * 128 + w * 32 + rt * 16 + l15;
      ridx = ridx < cntE ? ridx : cntE - 1;
#pragma unroll
      for (int kh = 0; kh < 2; ++kh) {
        const int u = quad + kh * 4;
        af[rt][kh] = *(const short8*)&grow[(ridx << 3) | (u ^ (ridx & 7))];
      }
    }

    float pos = 0.f, lns = 0.f;
    float ngrow_acc[2][4] = {{0.f, 0.f, 0.f, 0.f}, {0.f, 0.f, 0.f, 0.f}};
    const int nch = (cntE + 127) >> 7;
    for (int cc = 0; cc < nch; ++cc) {
      short8 bfr[8][2];
      bool cvalid[8];
#pragma unroll
      for (int ct = 0; ct < 8; ++ct) {
        const int cidx0 = cc * 128 + ct * 16 + l15;
        const int cidx = cidx0 < cntE ? cidx0 : cntE - 1;
        cvalid[ct] = cidx0 < cntE;
#pragma unroll
        for (int kh = 0; kh < 2; ++kh) {
          const int u = quad + kh * 4;
          bfr[ct][kh] = *(const short8*)&grow[(cidx << 3) | (u ^ (cidx & 7))];
        }
      }
      floatx4 acc[2][8];
#pragma unroll
      for (int rt = 0; rt < 2; ++rt)
#pragma unroll
        for (int ct = 0; ct < 8; ++ct) acc[rt][ct] = (floatx4){0.f, 0.f, 0.f, 0.f};
#pragma unroll
      for (int kh = 0; kh < 2; ++kh)
#pragma unroll
        for (int ct = 0; ct < 8; ++ct)
#pragma unroll
          for (int rt = 0; rt < 2; ++rt)
            acc[rt][ct] = __builtin_amdgcn_mfma_f32_16x16x32_bf16(
                af[rt][kh], bfr[ct][kh], acc[rt][ct], 0, 0, 0);
      // masked epilogue
#pragma unroll
      for (int rt = 0; rt < 2; ++rt) {
        const int rbase = rc * 128 + w * 32 + rt * 16 + quad * 4;
#pragma unroll
        for (int ct = 0; ct < 8; ++ct) {
#pragma unroll
          for (int r = 0; r < 4; ++r) {
            const bool ok = cvalid[ct] && (rbase + r < cntE);
            const float s = acc[rt][ct][r];
            const float d = __builtin_fmaf(s, LN2, -1.f);  // true sim - 1
            pos += ok ? d * d : 0.f;
            ngrow_acc[rt][r] += ok ? exp2_raw(s) : 0.f;  // bit-matches rowsum4
          }
        }
      }
    }
    // per-row: subtract from total, log, accumulate
#pragma unroll
    for (int rt = 0; rt < 2; ++rt)
#pragma unroll
      for (int r = 0; r < 4; ++r) {
        float g = ngrow_acc[rt][r];
#pragma unroll
        for (int m = 1; m < 16; m <<= 1) g += __shfl_xor(g, m, 64);
        const int ridx = rc * 128 + w * 32 + rt * 16 + quad * 4 + r;
        if (l15 == 0 && ridx < cntE) {
          const float nf = negtot[bN + list[ridx]] - g;
          lns += __logf(fmaxf(nf, 1e-30f));
        }
      }
    // block reduction
#pragma unroll
    for (int m = 1; m < 64; m <<= 1) {
      pos += __shfl_xor(pos, m, 64);
      lns += __shfl_xor(lns, m, 64);
    }
    if (lane == 0) {
      sPos[w] = pos;
      sLn[w] = lns;
    }
    __syncthreads();
    if (t == 0) {
      const float pt = sPos[0] + sPos[1] + sPos[2] + sPos[3];
      const float lt = sLn[0] + sLn[1] + sLn[2] + sLn[3];
      const float c = (float)cnt;
      // partial (this row-chunk's rows); denominators are per-instance
      atomicAdd(accum, WPc * pt / (c * c) + (1.f - WPc) * lt / c);
    }
  }
  if (t == 0) {
    __threadfence();
    const int old = atomicAdd(ticket, 1);
    if (old == GBLK - 1) {
      const float tot = atomicAdd(accum, 0.f);  // atomic read sees all adds
      out[0] = tot / (float)(Bsz * Isz);
    }
  }
}

// ---------------------------------------------------------------------------
extern "C" void kernel_launch(void* const* d_in, const int* in_sizes, int n_in,
                              void* d_out, int out_size, void* d_ws,
                              size_t ws_size, hipStream_t stream) {
  const float* x = (const float*)d_in[0];          // [B,N,D] fp32
  const uint8_t* label = (const uint8_t*)d_in[1];  // [B,I,N] bool
  float* out = (float*)d_out;

  // Workspace: [xb 1M bf16 = 2MB][negtot BN f32][accum][ticket][scales x3]
  uint16_t* xb = (uint16_t*)d_ws;
  float* negtot = (float*)(xb + (size_t)Bsz * Nsz * Dsz);
  float* accum = negtot + Bsz * Nsz;
  int* ticket = (int*)(accum + 1);
  float* scales = (float*)(ticket + 1);

  prep_kernel<<<(Bsz * Nsz * Dsz) / (256 * 4), 256, 0, stream>>>(
      x, xb, negtot, accum, ticket, scales);

  dim3 gridA(256, Bsz);  // 32 row-tiles x 8 col-groups
  rowsum4_kernel<<<gridA, 256, 0, stream>>>(xb, negtot, scales);

  dim3 gridB(Isz, Bsz, 2);
  gram2_kernel<<<gridB, 256, 0, stream>>>(xb, label, negtot, accum, ticket, out);
}

// Round 11
// 89.093 us; speedup vs baseline: 1.5186x; 1.5186x over previous
//
#include <hip/hip_runtime.h>
#include <stdint.h>

// Problem constants: B=4, I=32, N=4096, D=64, TEM=1.0, WP=0.5
#define Bsz 4
#define Isz 32
#define Nsz 4096
#define Dsz 64
#define WPc 0.5f
#define ALPHA 1.2011224087864498f  // sqrt(log2(e)): folds 1/ln2 into the data
#define LN2 0.69314718055994531f
#define LSZ2 256                   // member-list capacity (mean 128, sd 11)
#define GBLK (Isz * Bsz * 2)       // gram grid: 2 row-chunks per (b,i)

typedef __attribute__((ext_vector_type(8))) short short8;   // 8 bf16
typedef __attribute__((ext_vector_type(4))) float floatx4;  // MFMA C/D

__device__ inline uint16_t f2bf(float f) {
  uint32_t u = __float_as_uint(f);
  u += 0x7fffu + ((u >> 16) & 1u);  // RNE
  return (uint16_t)(u >> 16);
}
// exp2 via raw v_exp_f32; same op in rowsum and gram so negtot-negSub cancels.
__device__ inline float exp2_raw(float f) { return __builtin_amdgcn_exp2f(f); }

// ---------------------------------------------------------------------------
// Kernel 1: (a) convert x -> bf16(ALPHA*x) row-major xb [for gram2];
//           (b) blocks 0..511: ALSO emit xbf, the MFMA-fragment-ordered copy:
//               unit U = ((tile_g*2 + kh)*64 + lane), lane=(quad*16+m), holds
//               x[tile_g*16+m][kh*32+quad*8 .. +7] as 8 bf16 (16 B).
//               A wave's fragment load is then base+lane*16 = one dense 1 KB
//               global_load_dwordx4 -- the coalescing sweet spot.
//           (c) blocks 0..63: zero negtot / accum / ticket.
// ---------------------------------------------------------------------------
__global__ __launch_bounds__(256) void prep_kernel(
    const float* __restrict__ x, uint16_t* __restrict__ xb,
    uint4* __restrict__ xbf, float* __restrict__ negtot,
    float* __restrict__ accum, int* __restrict__ ticket) {
  const int t = threadIdx.x;
  const int blk = blockIdx.x;
  const int idx4 = (blk * 256 + t) * 4;
  const float4 v = *(const float4*)(x + idx4);
  ushort4 o;
  o.x = f2bf(v.x * ALPHA);
  o.y = f2bf(v.y * ALPHA);
  o.z = f2bf(v.z * ALPHA);
  o.w = f2bf(v.w * ALPHA);
  *(ushort4*)(xb + idx4) = o;

  if (blk < 512) {  // one 16B fragment unit per thread (128K units total)
    const int gid = blk * 256 + t;
    const int lane = gid & 63;
    const int kh = (gid >> 6) & 1;
    const int tile_g = gid >> 7;  // global tile: bb*256 + ti
    const int m = lane & 15;
    const int quad = lane >> 4;
    const size_t src = (size_t)(tile_g * 16 + m) * Dsz + kh * 32 + quad * 8;
    const float4 a = *(const float4*)(x + src);
    const float4 c = *(const float4*)(x + src + 4);
    ushort4 lo, hi;
    lo.x = f2bf(a.x * ALPHA); lo.y = f2bf(a.y * ALPHA);
    lo.z = f2bf(a.z * ALPHA); lo.w = f2bf(a.w * ALPHA);
    hi.x = f2bf(c.x * ALPHA); hi.y = f2bf(c.y * ALPHA);
    hi.z = f2bf(c.z * ALPHA); hi.w = f2bf(c.w * ALPHA);
    ushort4* dst = (ushort4*)(xbf + gid);
    dst[0] = lo;
    dst[1] = hi;
  }
  if (blk < 64) {
    const int p = blk * 256 + t;  // 0..16383 rows
    negtot[p] = 0.f;
    if (p == 0) {
      accum[0] = 0.f;
      ticket[0] = 0;
    }
  }
}

// ---------------------------------------------------------------------------
// Kernel 2: LDS-free exp-rowsum on fragment-ordered xbf.
// Block = 4 waves = 128 rows x 512 cols. Wave w: row-tiles w*2, w*2+1
// (A-frags in regs all kernel). Col loop: 32 tiles in groups of 4; each
// group issues 8 dense 1KB loads (deep MLP), then 16 MFMA, then 32 exp2.
// No LDS, no barriers, no DMA state -> low VGPR, high occupancy.
// C/D layout: col = lane&15, row = (lane>>4)*4 + reg.
// ---------------------------------------------------------------------------
__global__ __launch_bounds__(256) void rowsum5_kernel(
    const uint4* __restrict__ xbf, float* __restrict__ negtot) {
  const int t = threadIdx.x;
  const int lane = t & 63;
  const int w = t >> 6;
  const int quad = lane >> 4;
  const int l15 = lane & 15;

  const int b = blockIdx.y;
  const int rt0 = (blockIdx.x >> 3) * 8;  // first of 8 row-tiles (128 rows)
  const int ct0 = (blockIdx.x & 7) * 32;  // first of 32 col-tiles (512 cols)
  const int tb = b * 256;                 // tile base for this batch

  // A fragments: wave w's two row-tiles, kept in regs.
  short8 af[2][2];
#pragma unroll
  for (int rt = 0; rt < 2; ++rt) {
    const int tile = tb + rt0 + w * 2 + rt;
#pragma unroll
    for (int kh = 0; kh < 2; ++kh)
      af[rt][kh] = *(const short8*)&xbf[(size_t)(tile * 2 + kh) * 64 + lane];
  }

  float negAll[2][4] = {{0.f, 0.f, 0.f, 0.f}, {0.f, 0.f, 0.f, 0.f}};

#pragma unroll 1
  for (int cg = 0; cg < 8; ++cg) {  // 8 groups of 4 col-tiles
    short8 bf[4][2];
#pragma unroll
    for (int ci = 0; ci < 4; ++ci) {
      const int tile = tb + ct0 + cg * 4 + ci;
#pragma unroll
      for (int kh = 0; kh < 2; ++kh)
        bf[ci][kh] = *(const short8*)&xbf[(size_t)(tile * 2 + kh) * 64 + lane];
    }
    floatx4 acc[2][4];
#pragma unroll
    for (int rt = 0; rt < 2; ++rt)
#pragma unroll
      for (int ci = 0; ci < 4; ++ci) acc[rt][ci] = (floatx4){0.f, 0.f, 0.f, 0.f};
#pragma unroll
    for (int kh = 0; kh < 2; ++kh)
#pragma unroll
      for (int ci = 0; ci < 4; ++ci)
#pragma unroll
        for (int rt = 0; rt < 2; ++rt)
          acc[rt][ci] = __builtin_amdgcn_mfma_f32_16x16x32_bf16(
              af[rt][kh], bf[ci][kh], acc[rt][ci], 0, 0, 0);
#pragma unroll
    for (int ci = 0; ci < 4; ++ci)
#pragma unroll
      for (int rt = 0; rt < 2; ++rt)
#pragma unroll
        for (int r = 0; r < 4; ++r) negAll[rt][r] += exp2_raw(acc[rt][ci][r]);
  }

  // reduce over the 16 l15 lanes; one atomic per row per block.
  const size_t bN = (size_t)b * Nsz;
  const int wrow0 = rt0 * 16 + w * 32;
#pragma unroll
  for (int rt = 0; rt < 2; ++rt)
#pragma unroll
    for (int r = 0; r < 4; ++r) {
      float g = negAll[rt][r];
#pragma unroll
      for (int m = 1; m < 16; m <<= 1) g += __shfl_xor(g, m, 64);
      if (l15 == 0)
        atomicAdd(&negtot[bN + wrow0 + rt * 16 + quad * 4 + r], g);
    }
}

// ---------------------------------------------------------------------------
// Kernel 3: per-instance Gram + finalize (round-9 gram2, unchanged; reads
// row-major xb; MFMA kh-chain and exp2 bit-match rowsum5 so the
// negtot - negSub subtraction cancels cleanly).
// ---------------------------------------------------------------------------
__global__ __launch_bounds__(256) void gram2_kernel(
    const uint16_t* __restrict__ xb, const uint8_t* __restrict__ label,
    const float* __restrict__ negtot, float* __restrict__ accum,
    int* __restrict__ ticket, float* __restrict__ out) {
  __shared__ int list[LSZ2];
  __shared__ int scnt;
  __shared__ uint4 grow[LSZ2 * 8];  // 32 KB swizzled member-row data
  __shared__ float sPos[4];
  __shared__ float sLn[4];

  const int t = threadIdx.x;
  const int lane = t & 63;
  const int w = t >> 6;
  const int quad = lane >> 4;
  const int l15 = lane & 15;
  const int i = blockIdx.x;
  const int b = blockIdx.y;
  const int rc = blockIdx.z;  // row-chunk 0/1
  const size_t bN = (size_t)b * Nsz;
  const uint16_t* xbB = xb + bN * Dsz;

  if (t == 0) scnt = 0;
  __syncthreads();
  {  // membership: 16 label bytes per thread
    const uint4 lv = ((const uint4*)(label + ((size_t)b * Isz + i) * Nsz))[t];
    const uint32_t words[4] = {lv.x, lv.y, lv.z, lv.w};
#pragma unroll
    for (int jw = 0; jw < 4; ++jw)
#pragma unroll
      for (int jb = 0; jb < 4; ++jb) {
        if ((words[jw] >> (jb * 8)) & 0xff) {
          const int idx = atomicAdd(&scnt, 1);
          if (idx < LSZ2) list[idx] = t * 16 + jw * 4 + jb;
        }
      }
  }
  __syncthreads();
  const int cnt = scnt;
  const int cntE = cnt < LSZ2 ? cnt : LSZ2;

  // stage member rows into swizzled LDS (once; shared by A and B frags)
  for (int s = t; s < cntE * 8; s += 256) {
    const int j = s >> 3, u = s & 7;
    grow[(j << 3) | (u ^ (j & 7))] =
        *(const uint4*)(xbB + (size_t)list[j] * Dsz + u * 8);
  }
  __syncthreads();

  const bool active = (cnt >= 5) && (rc * 128 < cntE);
  if (active) {
    // A fragments for this block's 128 rows (wave w: rows rc*128+w*32..+31)
    short8 af[2][2];
#pragma unroll
    for (int rt = 0; rt < 2; ++rt) {
      int ridx = rc * 128 + w * 32 + rt * 16 + l15;
      ridx = ridx < cntE ? ridx : cntE - 1;
#pragma unroll
      for (int kh = 0; kh < 2; ++kh) {
        const int u = quad + kh * 4;
        af[rt][kh] = *(const short8*)&grow[(ridx << 3) | (u ^ (ridx & 7))];
      }
    }

    float pos = 0.f, lns = 0.f;
    float ngrow_acc[2][4] = {{0.f, 0.f, 0.f, 0.f}, {0.f, 0.f, 0.f, 0.f}};
    const int nch = (cntE + 127) >> 7;
    for (int cc = 0; cc < nch; ++cc) {
      short8 bfr[8][2];
      bool cvalid[8];
#pragma unroll
      for (int ct = 0; ct < 8; ++ct) {
        const int cidx0 = cc * 128 + ct * 16 + l15;
        const int cidx = cidx0 < cntE ? cidx0 : cntE - 1;
        cvalid[ct] = cidx0 < cntE;
#pragma unroll
        for (int kh = 0; kh < 2; ++kh) {
          const int u = quad + kh * 4;
          bfr[ct][kh] = *(const short8*)&grow[(cidx << 3) | (u ^ (cidx & 7))];
        }
      }
      floatx4 acc[2][8];
#pragma unroll
      for (int rt = 0; rt < 2; ++rt)
#pragma unroll
        for (int ct = 0; ct < 8; ++ct) acc[rt][ct] = (floatx4){0.f, 0.f, 0.f, 0.f};
#pragma unroll
      for (int kh = 0; kh < 2; ++kh)
#pragma unroll
        for (int ct = 0; ct < 8; ++ct)
#pragma unroll
          for (int rt = 0; rt < 2; ++rt)
            acc[rt][ct] = __builtin_amdgcn_mfma_f32_16x16x32_bf16(
                af[rt][kh], bfr[ct][kh], acc[rt][ct], 0, 0, 0);
      // masked epilogue
#pragma unroll
      for (int rt = 0; rt < 2; ++rt) {
        const int rbase = rc * 128 + w * 32 + rt * 16 + quad * 4;
#pragma unroll
        for (int ct = 0; ct < 8; ++ct) {
#pragma unroll
          for (int r = 0; r < 4; ++r) {
            const bool ok = cvalid[ct] && (rbase + r < cntE);
            const float s = acc[rt][ct][r];
            const float d = __builtin_fmaf(s, LN2, -1.f);  // true sim - 1
            pos += ok ? d * d : 0.f;
            ngrow_acc[rt][r] += ok ? exp2_raw(s) : 0.f;  // bit-matches rowsum5
          }
        }
      }
    }
    // per-row: subtract from total, log, accumulate
#pragma unroll
    for (int rt = 0; rt < 2; ++rt)
#pragma unroll
      for (int r = 0; r < 4; ++r) {
        float g = ngrow_acc[rt][r];
#pragma unroll
        for (int m = 1; m < 16; m <<= 1) g += __shfl_xor(g, m, 64);
        const int ridx = rc * 128 + w * 32 + rt * 16 + quad * 4 + r;
        if (l15 == 0 && ridx < cntE) {
          const float nf = negtot[bN + list[ridx]] - g;
          lns += __logf(fmaxf(nf, 1e-30f));
        }
      }
    // block reduction
#pragma unroll
    for (int m = 1; m < 64; m <<= 1) {
      pos += __shfl_xor(pos, m, 64);
      lns += __shfl_xor(lns, m, 64);
    }
    if (lane == 0) {
      sPos[w] = pos;
      sLn[w] = lns;
    }
    __syncthreads();
    if (t == 0) {
      const float pt = sPos[0] + sPos[1] + sPos[2] + sPos[3];
      const float lt = sLn[0] + sLn[1] + sLn[2] + sLn[3];
      const float c = (float)cnt;
      // partial (this row-chunk's rows); denominators are per-instance
      atomicAdd(accum, WPc * pt / (c * c) + (1.f - WPc) * lt / c);
    }
  }
  if (t == 0) {
    __threadfence();
    const int old = atomicAdd(ticket, 1);
    if (old == GBLK - 1) {
      const float tot = atomicAdd(accum, 0.f);  // atomic read sees all adds
      out[0] = tot / (float)(Bsz * Isz);
    }
  }
}

// ---------------------------------------------------------------------------
extern "C" void kernel_launch(void* const* d_in, const int* in_sizes, int n_in,
                              void* d_out, int out_size, void* d_ws,
                              size_t ws_size, hipStream_t stream) {
  const float* x = (const float*)d_in[0];          // [B,N,D] fp32
  const uint8_t* label = (const uint8_t*)d_in[1];  // [B,I,N] bool
  float* out = (float*)d_out;

  // Workspace: [xb 2MB][xbf 2MB frag-ordered][negtot BN f32][accum][ticket]
  uint16_t* xb = (uint16_t*)d_ws;
  uint4* xbf = (uint4*)(xb + (size_t)Bsz * Nsz * Dsz);
  float* negtot = (float*)(xbf + (size_t)Bsz * Nsz * Dsz / 8);
  float* accum = negtot + Bsz * Nsz;
  int* ticket = (int*)(accum + 1);

  prep_kernel<<<(Bsz * Nsz * Dsz) / (256 * 4), 256, 0, stream>>>(
      x, xb, xbf, negtot, accum, ticket);

  dim3 gridA(256, Bsz);  // 32 row-tiles x 8 col-groups
  rowsum5_kernel<<<gridA, 256, 0, stream>>>(xbf, negtot);

  dim3 gridB(Isz, Bsz, 2);
  gram2_kernel<<<gridB, 256, 0, stream>>>(xb, label, negtot, accum, ticket, out);
}

// Round 12
// 84.392 us; speedup vs baseline: 1.6032x; 1.0557x over previous
//
#include <hip/hip_runtime.h>
#include <stdint.h>

// Problem constants: B=4, I=32, N=4096, D=64, TEM=1.0, WP=0.5
#define Bsz 4
#define Isz 32
#define Nsz 4096
#define Dsz 64
#define WPc 0.5f
#define ALPHA 1.2011224087864498f  // sqrt(log2(e)): folds 1/ln2 into the data
#define LN2 0.69314718055994531f
#define LSZ2 256                   // member-list capacity (mean 128, sd 11)
#define GBLK (Isz * Bsz * 2)       // gram grid: 2 row-chunks per (b,i)

typedef __attribute__((ext_vector_type(8))) short short8;   // 8 bf16
typedef __attribute__((ext_vector_type(4))) float floatx4;  // MFMA C/D

__device__ inline uint16_t f2bf(float f) {
  uint32_t u = __float_as_uint(f);
  u += 0x7fffu + ((u >> 16) & 1u);  // RNE
  return (uint16_t)(u >> 16);
}
// exp2 via raw v_exp_f32; same op in rowsum and gram so negtot-negSub cancels.
__device__ inline float exp2_raw(float f) { return __builtin_amdgcn_exp2f(f); }

// ---------------------------------------------------------------------------
// Kernel 1: build xbf, the MFMA-fragment-ordered bf16(ALPHA*x):
//   unit U = (tile_g*2 + kh)*64 + lane, lane = quad*16 + m, holds
//   x[tile_g*16 + m][kh*32 + quad*8 .. +7] as 8 bf16 (16 B).
// A wave's fragment load is then base + lane*16 -> one dense 1 KB
// global_load_dwordx4. Each thread converts one unit (reads 32B = 1 sector).
// Blocks 0..63 also zero negtot / accum / ticket. No row-major copy anymore.
// ---------------------------------------------------------------------------
__global__ __launch_bounds__(256) void prep_kernel(
    const float* __restrict__ x, uint4* __restrict__ xbf,
    float* __restrict__ negtot, float* __restrict__ accum,
    int* __restrict__ ticket) {
  const int gid = blockIdx.x * 256 + threadIdx.x;  // 0..131071 units
  const int m = gid & 15;
  const int quad = (gid >> 4) & 3;
  const int kh = (gid >> 6) & 1;
  const int tile_g = gid >> 7;  // global 16-row tile (spans batches)
  const size_t src = (size_t)(tile_g * 16 + m) * Dsz + kh * 32 + quad * 8;
  const float4 a = *(const float4*)(x + src);
  const float4 c = *(const float4*)(x + src + 4);
  ushort4 lo, hi;
  lo.x = f2bf(a.x * ALPHA); lo.y = f2bf(a.y * ALPHA);
  lo.z = f2bf(a.z * ALPHA); lo.w = f2bf(a.w * ALPHA);
  hi.x = f2bf(c.x * ALPHA); hi.y = f2bf(c.y * ALPHA);
  hi.z = f2bf(c.z * ALPHA); hi.w = f2bf(c.w * ALPHA);
  ushort4* dst = (ushort4*)(xbf + gid);
  dst[0] = lo;
  dst[1] = hi;

  if (blockIdx.x < 64) {
    negtot[gid] = 0.f;  // gid < 16384 here
    if (gid == 0) {
      accum[0] = 0.f;
      ticket[0] = 0;
    }
  }
}

// ---------------------------------------------------------------------------
// Kernel 2: LDS-free exp-rowsum on fragment-ordered xbf, balanced tiles.
// Each wave INDEPENDENTLY covers 64 rows x 256 cols (4 row-tiles x 16
// col-tiles): traffic/wave = (4+16) tiles x 2KB = 40KB -> 164 MB total
// (was 278 MB at 2x32). Col loop: 8 groups of 2 tiles; 4 dense 1KB loads,
// 16 MFMA, 32 exp2 per group. No LDS, no barriers; VGPR ~110 ->
// __launch_bounds__(256,4) = 16 waves/CU for TLP latency cover.
// C/D layout: col = lane&15, row = (lane>>4)*4 + reg.
// ---------------------------------------------------------------------------
__global__ __launch_bounds__(256, 4) void rowsum6_kernel(
    const uint4* __restrict__ xbf, float* __restrict__ negtot) {
  const int t = threadIdx.x;
  const int lane = t & 63;
  const int w = t >> 6;
  const int quad = lane >> 4;
  const int l15 = lane & 15;

  const int b = blockIdx.y;
  const int gw = blockIdx.x * 4 + w;  // wave id within batch: 0..1023
  const int rg = gw >> 4;             // 64 row-groups of 64 rows
  const int cg = gw & 15;             // 16 col-groups of 256 cols
  const int tb = b * 256;             // tile base for this batch

  // A fragments: this wave's 4 row-tiles, kept in regs all kernel.
  short8 af[4][2];
#pragma unroll
  for (int i = 0; i < 4; ++i) {
    const int tile = tb + rg * 4 + i;
#pragma unroll
    for (int kh = 0; kh < 2; ++kh)
      af[i][kh] = *(const short8*)&xbf[(size_t)(tile * 2 + kh) * 64 + lane];
  }

  float negAll[4][4];
#pragma unroll
  for (int i = 0; i < 4; ++i)
#pragma unroll
    for (int r = 0; r < 4; ++r) negAll[i][r] = 0.f;

#pragma unroll 1
  for (int g = 0; g < 8; ++g) {  // 8 groups of 2 col-tiles
    short8 bf[2][2];
#pragma unroll
    for (int c = 0; c < 2; ++c) {
      const int tile = tb + cg * 16 + g * 2 + c;
#pragma unroll
      for (int kh = 0; kh < 2; ++kh)
        bf[c][kh] = *(const short8*)&xbf[(size_t)(tile * 2 + kh) * 64 + lane];
    }
    floatx4 acc[4][2];
#pragma unroll
    for (int i = 0; i < 4; ++i)
#pragma unroll
      for (int c = 0; c < 2; ++c) acc[i][c] = (floatx4){0.f, 0.f, 0.f, 0.f};
#pragma unroll
    for (int kh = 0; kh < 2; ++kh)
#pragma unroll
      for (int c = 0; c < 2; ++c)
#pragma unroll
        for (int i = 0; i < 4; ++i)
          acc[i][c] = __builtin_amdgcn_mfma_f32_16x16x32_bf16(
              af[i][kh], bf[c][kh], acc[i][c], 0, 0, 0);
#pragma unroll
    for (int c = 0; c < 2; ++c)
#pragma unroll
      for (int i = 0; i < 4; ++i)
#pragma unroll
        for (int r = 0; r < 4; ++r) negAll[i][r] += exp2_raw(acc[i][c][r]);
  }

  // reduce over the 16 l15 lanes; one atomic instr per (row-tile, reg).
  const size_t bN = (size_t)b * Nsz;
  const int wrow0 = rg * 64;
#pragma unroll
  for (int i = 0; i < 4; ++i)
#pragma unroll
    for (int r = 0; r < 4; ++r) {
      float g = negAll[i][r];
#pragma unroll
      for (int m = 1; m < 16; m <<= 1) g += __shfl_xor(g, m, 64);
      if (l15 == 0)
        atomicAdd(&negtot[bN + wrow0 + i * 16 + quad * 4 + r], g);
    }
}

// ---------------------------------------------------------------------------
// Kernel 3: per-instance Gram + finalize. Same as round 9/11 except member
// rows are staged from xbf (row p, dims u*8..+7 live at unit
// ((p>>4)*2 + (u>>2))*64 + (u&3)*16 + (p&15)) -- same bf16 bits, same
// kh-chain as rowsum6, so negtot - negSub cancels cleanly.
// ---------------------------------------------------------------------------
__global__ __launch_bounds__(256) void gram2_kernel(
    const uint4* __restrict__ xbf, const uint8_t* __restrict__ label,
    const float* __restrict__ negtot, float* __restrict__ accum,
    int* __restrict__ ticket, float* __restrict__ out) {
  __shared__ int list[LSZ2];
  __shared__ int scnt;
  __shared__ uint4 grow[LSZ2 * 8];  // 32 KB swizzled member-row data
  __shared__ float sPos[4];
  __shared__ float sLn[4];

  const int t = threadIdx.x;
  const int lane = t & 63;
  const int w = t >> 6;
  const int quad = lane >> 4;
  const int l15 = lane & 15;
  const int i = blockIdx.x;
  const int b = blockIdx.y;
  const int rc = blockIdx.z;  // row-chunk 0/1
  const size_t bN = (size_t)b * Nsz;
  const int tb = b * 256;

  if (t == 0) scnt = 0;
  __syncthreads();
  {  // membership: 16 label bytes per thread
    const uint4 lv = ((const uint4*)(label + ((size_t)b * Isz + i) * Nsz))[t];
    const uint32_t words[4] = {lv.x, lv.y, lv.z, lv.w};
#pragma unroll
    for (int jw = 0; jw < 4; ++jw)
#pragma unroll
      for (int jb = 0; jb < 4; ++jb) {
        if ((words[jw] >> (jb * 8)) & 0xff) {
          const int idx = atomicAdd(&scnt, 1);
          if (idx < LSZ2) list[idx] = t * 16 + jw * 4 + jb;
        }
      }
  }
  __syncthreads();
  const int cnt = scnt;
  const int cntE = cnt < LSZ2 ? cnt : LSZ2;

  // stage member rows into swizzled LDS from fragment-ordered xbf
  for (int s = t; s < cntE * 8; s += 256) {
    const int j = s >> 3, u = s & 7;
    const int p = list[j];
    const size_t unit =
        (size_t)((tb + (p >> 4)) * 2 + (u >> 2)) * 64 + (u & 3) * 16 + (p & 15);
    grow[(j << 3) | (u ^ (j & 7))] = xbf[unit];
  }
  __syncthreads();

  const bool active = (cnt >= 5) && (rc * 128 < cntE);
  if (active) {
    // A fragments for this block's 128 rows (wave w: rows rc*128+w*32..+31)
    short8 af[2][2];
#pragma unroll
    for (int rt = 0; rt < 2; ++rt) {
      int ridx = rc * 128 + w * 32 + rt * 16 + l15;
      ridx = ridx < cntE ? ridx : cntE - 1;
#pragma unroll
      for (int kh = 0; kh < 2; ++kh) {
        const int u = quad + kh * 4;
        af[rt][kh] = *(const short8*)&grow[(ridx << 3) | (u ^ (ridx & 7))];
      }
    }

    float pos = 0.f, lns = 0.f;
    float ngrow_acc[2][4] = {{0.f, 0.f, 0.f, 0.f}, {0.f, 0.f, 0.f, 0.f}};
    const int nch = (cntE + 127) >> 7;
    for (int cc = 0; cc < nch; ++cc) {
      short8 bfr[8][2];
      bool cvalid[8];
#pragma unroll
      for (int ct = 0; ct < 8; ++ct) {
        const int cidx0 = cc * 128 + ct * 16 + l15;
        const int cidx = cidx0 < cntE ? cidx0 : cntE - 1;
        cvalid[ct] = cidx0 < cntE;
#pragma unroll
        for (int kh = 0; kh < 2; ++kh) {
          const int u = quad + kh * 4;
          bfr[ct][kh] = *(const short8*)&grow[(cidx << 3) | (u ^ (cidx & 7))];
        }
      }
      floatx4 acc[2][8];
#pragma unroll
      for (int rt = 0; rt < 2; ++rt)
#pragma unroll
        for (int ct = 0; ct < 8; ++ct) acc[rt][ct] = (floatx4){0.f, 0.f, 0.f, 0.f};
#pragma unroll
      for (int kh = 0; kh < 2; ++kh)
#pragma unroll
        for (int ct = 0; ct < 8; ++ct)
#pragma unroll
          for (int rt = 0; rt < 2; ++rt)
            acc[rt][ct] = __builtin_amdgcn_mfma_f32_16x16x32_bf16(
                af[rt][kh], bfr[ct][kh], acc[rt][ct], 0, 0, 0);
      // masked epilogue
#pragma unroll
      for (int rt = 0; rt < 2; ++rt) {
        const int rbase = rc * 128 + w * 32 + rt * 16 + quad * 4;
#pragma unroll
        for (int ct = 0; ct < 8; ++ct) {
#pragma unroll
          for (int r = 0; r < 4; ++r) {
            const bool ok = cvalid[ct] && (rbase + r < cntE);
            const float s = acc[rt][ct][r];
            const float d = __builtin_fmaf(s, LN2, -1.f);  // true sim - 1
            pos += ok ? d * d : 0.f;
            ngrow_acc[rt][r] += ok ? exp2_raw(s) : 0.f;  // bit-matches rowsum6
          }
        }
      }
    }
    // per-row: subtract from total, log, accumulate
#pragma unroll
    for (int rt = 0; rt < 2; ++rt)
#pragma unroll
      for (int r = 0; r < 4; ++r) {
        float g = ngrow_acc[rt][r];
#pragma unroll
        for (int m = 1; m < 16; m <<= 1) g += __shfl_xor(g, m, 64);
        const int ridx = rc * 128 + w * 32 + rt * 16 + quad * 4 + r;
        if (l15 == 0 && ridx < cntE) {
          const float nf = negtot[bN + list[ridx]] - g;
          lns += __logf(fmaxf(nf, 1e-30f));
        }
      }
    // block reduction
#pragma unroll
    for (int m = 1; m < 64; m <<= 1) {
      pos += __shfl_xor(pos, m, 64);
      lns += __shfl_xor(lns, m, 64);
    }
    if (lane == 0) {
      sPos[w] = pos;
      sLn[w] = lns;
    }
    __syncthreads();
    if (t == 0) {
      const float pt = sPos[0] + sPos[1] + sPos[2] + sPos[3];
      const float lt = sLn[0] + sLn[1] + sLn[2] + sLn[3];
      const float c = (float)cnt;
      // partial (this row-chunk's rows); denominators are per-instance
      atomicAdd(accum, WPc * pt / (c * c) + (1.f - WPc) * lt / c);
    }
  }
  if (t == 0) {
    __threadfence();
    const int old = atomicAdd(ticket, 1);
    if (old == GBLK - 1) {
      const float tot = atomicAdd(accum, 0.f);  // atomic read sees all adds
      out[0] = tot / (float)(Bsz * Isz);
    }
  }
}

// ---------------------------------------------------------------------------
extern "C" void kernel_launch(void* const* d_in, const int* in_sizes, int n_in,
                              void* d_out, int out_size, void* d_ws,
                              size_t ws_size, hipStream_t stream) {
  const float* x = (const float*)d_in[0];          // [B,N,D] fp32
  const uint8_t* label = (const uint8_t*)d_in[1];  // [B,I,N] bool
  float* out = (float*)d_out;

  // Workspace: [xbf 2MB frag-ordered][negtot BN f32][accum][ticket]
  uint4* xbf = (uint4*)d_ws;
  float* negtot = (float*)(xbf + (size_t)Bsz * Nsz * Dsz / 8);
  float* accum = negtot + Bsz * Nsz;
  int* ticket = (int*)(accum + 1);

  prep_kernel<<<512, 256, 0, stream>>>(x, xbf, negtot, accum, ticket);

  dim3 gridA(256, Bsz);  // 1024 waves/batch: 64 row-groups x 16 col-groups
  rowsum6_kernel<<<gridA, 256, 0, stream>>>(xbf, negtot);

  dim3 gridB(Isz, Bsz, 2);
  gram2_kernel<<<gridB, 256, 0, stream>>>(xbf, label, negtot, accum, ticket, out);
}